// Round 5
// baseline (34.887 us; speedup 1.0000x reference)
//
#include <hip/hip_runtime.h>

// Problem constants
#define BB 32
#define NN 10
#define IN_DIM 65536
#define HEADS 8
#define DD 8
#define ROWS (BB*NN)            // 320 "bn" rows
#define K4 (IN_DIM/4)           // 16384 float4 per row
#define SPLITS 16
#define KSPLIT (K4/SPLITS)      // 1024 float4 per block
#define KHALF (KSPLIT/2)        // 512 float4 per k-half
#define RGROUP 5                // rows per block -> 64 groups x 16 splits = 1024 blocks = exactly 4/CU
#define NGROUPS (ROWS/RGROUP)   // 64

// ---------------------------------------------------------------------------
// Kernel 1: Wh[h][k] = sum_{d=0..7} W[h*8+d][k]   (W is 64 x 65536 row-major)
// ---------------------------------------------------------------------------
__global__ __launch_bounds__(256) void wreduce_kernel(const float* __restrict__ W,
                                                      float* __restrict__ Wh) {
    int idx = blockIdx.x * blockDim.x + threadIdx.x;   // 0 .. 8*16384-1
    int h  = idx >> 14;
    int k4 = idx & 16383;
    const float4* W4 = (const float4*)W;
    float4 s = make_float4(0.f, 0.f, 0.f, 0.f);
#pragma unroll
    for (int d = 0; d < DD; ++d) {
        float4 v = W4[(h * DD + d) * K4 + k4];
        s.x += v.x; s.y += v.y; s.z += v.z; s.w += v.w;
    }
    ((float4*)Wh)[h * K4 + k4] = s;
}

// ---------------------------------------------------------------------------
// Kernel 2: partial GEMV. s[bn][h] = x[bn][:] . Wh[h][:]
// grid = NGROUPS * SPLITS = 1024 blocks (exactly 4 resident blocks/CU at
// <=128 VGPR -> one scheduling round, no partial-round tail).
// Block (g, split): rows g*5..g*5+4, k-chunk [split*KSPLIT, +KSPLIT).
// Wave w: khalf = w>>1, head group hg = w&1 (heads 4hg..4hg+3).
// Writes partials[split][bn][h]  (16 x 320 x 8 floats)
// ---------------------------------------------------------------------------
__global__ __launch_bounds__(256, 4) void gemv_part_kernel(const float* __restrict__ x,
                                                           const float* __restrict__ Wh,
                                                           float* __restrict__ partials) {
    const int g     = blockIdx.x % NGROUPS;
    const int split = blockIdx.x / NGROUPS;
    const int t     = threadIdx.x;
    const int lane  = t & 63;
    const int wave  = t >> 6;      // 0..3
    const int hg    = wave & 1;    // head group: heads hg*4 .. hg*4+3
    const int kh    = wave >> 1;   // k-half

    const float4* x4  = (const float4*)x;
    const float4* Wh4 = (const float4*)Wh;

    float acc[RGROUP][4];
#pragma unroll
    for (int r = 0; r < RGROUP; ++r)
#pragma unroll
        for (int h = 0; h < 4; ++h) acc[r][h] = 0.f;

    const int kbase = split * KSPLIT + kh * KHALF + lane;

#pragma unroll 2
    for (int i = 0; i < KHALF / 64; ++i) {   // 8 iterations
        const int k4 = kbase + i * 64;
        float4 wv[4];
#pragma unroll
        for (int h = 0; h < 4; ++h) wv[h] = Wh4[(size_t)(hg * 4 + h) * K4 + k4];
#pragma unroll
        for (int r = 0; r < RGROUP; ++r) {
            float4 xv = x4[(size_t)(g * RGROUP + r) * K4 + k4];
#pragma unroll
            for (int h = 0; h < 4; ++h) {
                acc[r][h] += xv.x * wv[h].x + xv.y * wv[h].y
                           + xv.z * wv[h].z + xv.w * wv[h].w;
            }
        }
    }

    // reduce each of the 20 accumulators across the 64 lanes
#pragma unroll
    for (int r = 0; r < RGROUP; ++r) {
#pragma unroll
        for (int h = 0; h < 4; ++h) {
            float v = acc[r][h];
#pragma unroll
            for (int off = 32; off > 0; off >>= 1) v += __shfl_down(v, off);
            acc[r][h] = v;
        }
    }

    __shared__ float red[4][RGROUP * 4];
    if (lane == 0) {
#pragma unroll
        for (int r = 0; r < RGROUP; ++r)
#pragma unroll
            for (int h = 0; h < 4; ++h)
                red[wave][r * 4 + h] = acc[r][h];
    }
    __syncthreads();

    // combine the two k-halves; t<40 covers (r 0..4, h 0..7)
    if (t < RGROUP * HEADS) {
        const int r   = t >> 3;
        const int h   = t & 7;
        const int hgr = h >> 2;
        const int hh  = h & 3;
        float v = red[hgr][r * 4 + hh] + red[hgr + 2][r * 4 + hh];
        const int bn = g * RGROUP + r;
        partials[(size_t)split * (ROWS * HEADS) + bn * HEADS + h] = v;
    }
}

// ---------------------------------------------------------------------------
// Kernel 3: out[bn][h*10+m] = relu( (sum_s partials[s][bn][h]) * adj[bn][m] )
// ---------------------------------------------------------------------------
__global__ __launch_bounds__(256) void finalize_kernel(const float* __restrict__ partials,
                                                       const float* __restrict__ adj,
                                                       float* __restrict__ out,
                                                       int out_size) {
    int idx = blockIdx.x * blockDim.x + threadIdx.x;
    if (idx >= out_size) return;
    int bn  = idx / (HEADS * NN);
    int rem = idx % (HEADS * NN);
    int h = rem / NN;
    int m = rem % NN;
    float s = 0.f;
#pragma unroll
    for (int sp = 0; sp < SPLITS; ++sp)
        s += partials[(size_t)sp * (ROWS * HEADS) + bn * HEADS + h];
    float v = s * adj[bn * NN + m];
    out[idx] = v > 0.f ? v : 0.f;
}

extern "C" void kernel_launch(void* const* d_in, const int* in_sizes, int n_in,
                              void* d_out, int out_size, void* d_ws, size_t ws_size,
                              hipStream_t stream) {
    const float* x   = (const float*)d_in[0];   // (32,10,65536)
    const float* adj = (const float*)d_in[1];   // (32,10,10)
    const float* W   = (const float*)d_in[2];   // (64,65536)
    float* out = (float*)d_out;                 // (32,10,80) = 25600 floats

    // workspace layout: Wh (8*65536 f = 2 MiB) | partials (16*2560 f)
    float* Wh       = (float*)d_ws;
    float* partials = Wh + (size_t)HEADS * IN_DIM;

    // K1: reduce W -> Wh. 8*16384 = 131072 threads.
    wreduce_kernel<<<(HEADS * K4) / 256, 256, 0, stream>>>(W, Wh);

    // K2: partial GEMV. 64 groups x 16 splits = 1024 blocks.
    gemv_part_kernel<<<NGROUPS * SPLITS, 256, 0, stream>>>(x, Wh, partials);

    // K3: finalize. 25600 outputs.
    finalize_kernel<<<(out_size + 255) / 256, 256, 0, stream>>>(partials, adj, out, out_size);
}

// Round 6
// 29.346 us; speedup vs baseline: 1.1888x; 1.1888x over previous
//
#include <hip/hip_runtime.h>
#include <hip/hip_bf16.h>

// Problem constants
#define BB 32
#define NN 10
#define IN_DIM 65536
#define HEADS 8
#define DD 8
#define ROWS (BB*NN)          // 320
#define MTILES (ROWS/16)      // 20
#define KBLOCKS (IN_DIM/32)   // 2048 MFMA k-steps
#define KSPLITS 256           // k-splits; 8 kblocks per split
#define KB_PER_SPLIT (KBLOCKS/KSPLITS)   // 8
#define KGRPS (KSPLITS/4)     // 64 (4 ksplits folded per block)

typedef __attribute__((ext_vector_type(8))) short bf16x8;
typedef __attribute__((ext_vector_type(4))) float f32x4;

static __device__ __forceinline__ short f2bf(float f) {
    __hip_bfloat16 h = __float2bfloat16(f);
    return *reinterpret_cast<short*>(&h);
}

// ---------------------------------------------------------------------------
// Kernel 1: build B-fragments.  B[k][h] = sum_d W[h*8+d][k], stored bf16 in the
// exact mfma_16x16x32 B-operand per-lane layout:
//   Bfrag[kblock*64 + lane][i] = B[kblock*32 + (lane>>4)*8 + i][lane&15]
// (cols 8..15 zero). One thread per (kblock, lane).
// ---------------------------------------------------------------------------
__global__ __launch_bounds__(256) void wreduce_kernel(const float* __restrict__ W,
                                                      bf16x8* __restrict__ Bfrag) {
    int tid    = blockIdx.x * 256 + threadIdx.x;   // 0 .. 131071
    int kblock = tid >> 6;                         // 0 .. 2047
    int lane   = tid & 63;
    int head   = lane & 15;
    int kq     = lane >> 4;                        // 0..3
    bf16x8 o = {0,0,0,0,0,0,0,0};
    if (head < HEADS) {
        float s0=0,s1=0,s2=0,s3=0,s4=0,s5=0,s6=0,s7=0;
        const float* wbase = W + (size_t)(head * DD) * IN_DIM + kblock * 32 + kq * 8;
#pragma unroll
        for (int d = 0; d < DD; ++d) {
            const float4* p = (const float4*)(wbase + (size_t)d * IN_DIM);
            float4 lo = p[0], hi = p[1];
            s0 += lo.x; s1 += lo.y; s2 += lo.z; s3 += lo.w;
            s4 += hi.x; s5 += hi.y; s6 += hi.z; s7 += hi.w;
        }
        o[0]=f2bf(s0); o[1]=f2bf(s1); o[2]=f2bf(s2); o[3]=f2bf(s3);
        o[4]=f2bf(s4); o[5]=f2bf(s5); o[6]=f2bf(s6); o[7]=f2bf(s7);
    }
    Bfrag[tid] = o;
}

// ---------------------------------------------------------------------------
// Kernel 2: MFMA GEMV.  D[m][n] = sum_k A[m][k] B[k][n], A = x (bf16-cvt on the
// fly), B = prebaked Bfrag.  Wave = (mtile, ksplit of 8 kblocks).  Block's 4
// waves share one mtile and 4 adjacent ksplits; folded in LDS.
// A-frag: lane l holds A[l&15][(l>>4)*8 + i]  -> 8 consecutive floats of one
// row: lanes {l, l+16, l+32, l+48} cover a full 128B line (coalesced, x read
// exactly once device-wide).
// C/D: col = lane&15 (head), row = (lane>>4)*4 + reg (m89-verified).
// Writes partials[kgrp][row][head]  (64 x 320 x 8 f32).
// ---------------------------------------------------------------------------
__global__ __launch_bounds__(256) void gemv_mfma_kernel(const float* __restrict__ x,
                                                        const bf16x8* __restrict__ Bfrag,
                                                        float* __restrict__ partials) {
    const int t     = threadIdx.x;
    const int lane  = t & 63;
    const int wave  = t >> 6;                 // 0..3
    const int mtile = blockIdx.x >> 6;        // 0..19
    const int kgrp  = blockIdx.x & 63;        // 0..63
    const int ksplit = kgrp * 4 + wave;       // 0..255

    const int row = mtile * 16 + (lane & 15);
    const int kq  = lane >> 4;                // 0..3
    const float* xrow = x + (size_t)row * IN_DIM + kq * 8;

    f32x4 acc = {0.f, 0.f, 0.f, 0.f};
    const int kb0 = ksplit * KB_PER_SPLIT;

#pragma unroll
    for (int s = 0; s < KB_PER_SPLIT; ++s) {
        const int kb = kb0 + s;
        const float4* xa = (const float4*)(xrow + kb * 32);
        float4 lo = xa[0], hi = xa[1];
        bf16x8 a;
        a[0]=f2bf(lo.x); a[1]=f2bf(lo.y); a[2]=f2bf(lo.z); a[3]=f2bf(lo.w);
        a[4]=f2bf(hi.x); a[5]=f2bf(hi.y); a[6]=f2bf(hi.z); a[7]=f2bf(hi.w);
        bf16x8 b = Bfrag[(size_t)kb * 64 + lane];
        acc = __builtin_amdgcn_mfma_f32_16x16x32_bf16(a, b, acc, 0, 0, 0);
    }

    // fold the block's 4 ksplits
    __shared__ float red[4][64][4];
    red[wave][lane][0] = acc[0];
    red[wave][lane][1] = acc[1];
    red[wave][lane][2] = acc[2];
    red[wave][lane][3] = acc[3];
    __syncthreads();

    const int head = lane & 15;
    if (wave == 0 && head < HEADS) {
        const int r0 = (lane >> 4) * 4;
#pragma unroll
        for (int j = 0; j < 4; ++j) {
            float v = red[0][lane][j] + red[1][lane][j]
                    + red[2][lane][j] + red[3][lane][j];
            partials[((size_t)kgrp * ROWS + (mtile * 16 + r0 + j)) * HEADS + head] = v;
        }
    }
}

// ---------------------------------------------------------------------------
// Kernel 3: out[bn][h*10+m] = relu( (sum_g partials[g][bn][h]) * adj[bn][m] )
// One thread per (bn, h) pair; writes 10 consecutive outputs.
// ---------------------------------------------------------------------------
__global__ __launch_bounds__(256) void finalize_kernel(const float* __restrict__ partials,
                                                       const float* __restrict__ adj,
                                                       float* __restrict__ out) {
    int t = blockIdx.x * 256 + threadIdx.x;     // 0..2559
    if (t >= ROWS * HEADS) return;
    int bn = t >> 3;
    int h  = t & 7;
    float s = 0.f;
#pragma unroll 8
    for (int g = 0; g < KGRPS; ++g)
        s += partials[((size_t)g * ROWS + bn) * HEADS + h];
    float* o = out + bn * (HEADS * NN) + h * NN;
    const float* a = adj + bn * NN;
#pragma unroll
    for (int m = 0; m < NN; ++m) {
        float v = s * a[m];
        o[m] = v > 0.f ? v : 0.f;
    }
}

extern "C" void kernel_launch(void* const* d_in, const int* in_sizes, int n_in,
                              void* d_out, int out_size, void* d_ws, size_t ws_size,
                              hipStream_t stream) {
    const float* x   = (const float*)d_in[0];   // (32,10,65536)
    const float* adj = (const float*)d_in[1];   // (32,10,10)
    const float* W   = (const float*)d_in[2];   // (64,65536)
    float* out = (float*)d_out;                 // (32,10,80)

    // workspace: Bfrag (2048*64 bf16x8 = 2 MiB) | partials (64*320*8 f32 = 640 KiB)
    bf16x8* Bfrag   = (bf16x8*)d_ws;
    float* partials = (float*)(Bfrag + (size_t)KBLOCKS * 64);

    // K1: W -> bf16 B-fragments. 2048 kblocks x 64 lanes = 512 blocks.
    wreduce_kernel<<<(KBLOCKS * 64) / 256, 256, 0, stream>>>(W, Bfrag);

    // K2: MFMA GEMV. 20 mtiles x 64 kgrps = 1280 blocks.
    gemv_mfma_kernel<<<MTILES * KGRPS, 256, 0, stream>>>(x, Bfrag, partials);

    // K3: finalize. 2560 (bn,h) pairs.
    finalize_kernel<<<(ROWS * HEADS + 255) / 256, 256, 0, stream>>>(partials, adj, out);
}

// Round 7
// 28.845 us; speedup vs baseline: 1.2095x; 1.0174x over previous
//
#include <hip/hip_runtime.h>
#include <hip/hip_bf16.h>

// Problem constants
#define BB 32
#define NN 10
#define IN_DIM 65536
#define HEADS 8
#define DD 8
#define ROWS (BB*NN)          // 320
#define MTILES (ROWS/16)      // 20
#define KBLOCKS (IN_DIM/32)   // 2048 MFMA k-steps
#define KSPLITS 256           // k-splits; 8 kblocks per split
#define KB_PER_SPLIT (KBLOCKS/KSPLITS)   // 8
#define KGRPS (KSPLITS/4)     // 64 (4 ksplits folded per block)

typedef __attribute__((ext_vector_type(8))) short bf16x8;
typedef __attribute__((ext_vector_type(4))) float f32x4;

static __device__ __forceinline__ short f2bf(float f) {
    __hip_bfloat16 h = __float2bfloat16(f);
    return *reinterpret_cast<short*>(&h);
}

// ---------------------------------------------------------------------------
// Kernel 1: build B-fragments.  B[k][h] = sum_d W[h*8+d][k], stored bf16 in the
// exact mfma_16x16x32 B-operand per-lane layout:
//   Bfrag[kblock*64 + lane][i] = B[kblock*32 + (lane>>4)*8 + i][lane&15]
// (cols 8..15 zero). One thread per (kblock, lane).
// ---------------------------------------------------------------------------
__global__ __launch_bounds__(256) void wreduce_kernel(const float* __restrict__ W,
                                                      bf16x8* __restrict__ Bfrag) {
    int tid    = blockIdx.x * 256 + threadIdx.x;   // 0 .. 131071
    int kblock = tid >> 6;                         // 0 .. 2047
    int lane   = tid & 63;
    int head   = lane & 15;
    int kq     = lane >> 4;                        // 0..3
    bf16x8 o = {0,0,0,0,0,0,0,0};
    if (head < HEADS) {
        float s0=0,s1=0,s2=0,s3=0,s4=0,s5=0,s6=0,s7=0;
        const float* wbase = W + (size_t)(head * DD) * IN_DIM + kblock * 32 + kq * 8;
#pragma unroll
        for (int d = 0; d < DD; ++d) {
            const float4* p = (const float4*)(wbase + (size_t)d * IN_DIM);
            float4 lo = p[0], hi = p[1];
            s0 += lo.x; s1 += lo.y; s2 += lo.z; s3 += lo.w;
            s4 += hi.x; s5 += hi.y; s6 += hi.z; s7 += hi.w;
        }
        o[0]=f2bf(s0); o[1]=f2bf(s1); o[2]=f2bf(s2); o[3]=f2bf(s3);
        o[4]=f2bf(s4); o[5]=f2bf(s5); o[6]=f2bf(s6); o[7]=f2bf(s7);
    }
    Bfrag[tid] = o;
}

// ---------------------------------------------------------------------------
// Kernel 2: MFMA GEMV.  D[m][n] = sum_k A[m][k] B[k][n].
// grid = 20 mtiles x 64 kgrps = 1280 blocks; __launch_bounds__(256,5) caps
// VGPR at 102 so 5 blocks/CU reside -> entire grid co-resident, no tail round.
// Pair-loop (unroll 2) keeps <=12 loads in the scheduling window; dual
// accumulators break the serial MFMA chain (statically indexed).
// ---------------------------------------------------------------------------
__global__ __launch_bounds__(256, 5) void gemv_mfma_kernel(const float* __restrict__ x,
                                                           const bf16x8* __restrict__ Bfrag,
                                                           float* __restrict__ partials) {
    const int t     = threadIdx.x;
    const int lane  = t & 63;
    const int wave  = t >> 6;                 // 0..3
    const int mtile = blockIdx.x >> 6;        // 0..19
    const int kgrp  = blockIdx.x & 63;        // 0..63
    const int ksplit = kgrp * 4 + wave;       // 0..255

    const int row = mtile * 16 + (lane & 15);
    const int kq  = lane >> 4;                // 0..3
    const float* xrow = x + (size_t)row * IN_DIM + kq * 8;

    f32x4 acc0 = {0.f, 0.f, 0.f, 0.f};
    f32x4 acc1 = {0.f, 0.f, 0.f, 0.f};
    const int kb0 = ksplit * KB_PER_SPLIT;

#pragma unroll 2
    for (int s = 0; s < KB_PER_SPLIT; s += 2) {
        const int kbA = kb0 + s;
        const int kbB = kbA + 1;
        const float4* xa = (const float4*)(xrow + kbA * 32);
        const float4* xb = (const float4*)(xrow + kbB * 32);
        float4 alo = xa[0], ahi = xa[1];
        float4 blo = xb[0], bhi = xb[1];
        bf16x8 fbA = Bfrag[(size_t)kbA * 64 + lane];
        bf16x8 fbB = Bfrag[(size_t)kbB * 64 + lane];
        bf16x8 aA, aB;
        aA[0]=f2bf(alo.x); aA[1]=f2bf(alo.y); aA[2]=f2bf(alo.z); aA[3]=f2bf(alo.w);
        aA[4]=f2bf(ahi.x); aA[5]=f2bf(ahi.y); aA[6]=f2bf(ahi.z); aA[7]=f2bf(ahi.w);
        aB[0]=f2bf(blo.x); aB[1]=f2bf(blo.y); aB[2]=f2bf(blo.z); aB[3]=f2bf(blo.w);
        aB[4]=f2bf(bhi.x); aB[5]=f2bf(bhi.y); aB[6]=f2bf(bhi.z); aB[7]=f2bf(bhi.w);
        acc0 = __builtin_amdgcn_mfma_f32_16x16x32_bf16(aA, fbA, acc0, 0, 0, 0);
        acc1 = __builtin_amdgcn_mfma_f32_16x16x32_bf16(aB, fbB, acc1, 0, 0, 0);
    }

    f32x4 acc = acc0 + acc1;

    // fold the block's 4 ksplits
    __shared__ float red[4][64][4];
    red[wave][lane][0] = acc[0];
    red[wave][lane][1] = acc[1];
    red[wave][lane][2] = acc[2];
    red[wave][lane][3] = acc[3];
    __syncthreads();

    const int head = lane & 15;
    if (wave == 0 && head < HEADS) {
        const int r0 = (lane >> 4) * 4;
#pragma unroll
        for (int j = 0; j < 4; ++j) {
            float v = red[0][lane][j] + red[1][lane][j]
                    + red[2][lane][j] + red[3][lane][j];
            partials[((size_t)kgrp * ROWS + (mtile * 16 + r0 + j)) * HEADS + head] = v;
        }
    }
}

// ---------------------------------------------------------------------------
// Kernel 3: out[bn][h*10+m] = relu( (sum_g partials[g][bn][h]) * adj[bn][m] )
// One thread per (bn, h) pair; writes 10 consecutive outputs.
// ---------------------------------------------------------------------------
__global__ __launch_bounds__(256) void finalize_kernel(const float* __restrict__ partials,
                                                       const float* __restrict__ adj,
                                                       float* __restrict__ out) {
    int t = blockIdx.x * 256 + threadIdx.x;     // 0..2559
    if (t >= ROWS * HEADS) return;
    int bn = t >> 3;
    int h  = t & 7;
    float s = 0.f;
#pragma unroll 8
    for (int g = 0; g < KGRPS; ++g)
        s += partials[((size_t)g * ROWS + bn) * HEADS + h];
    float* o = out + bn * (HEADS * NN) + h * NN;
    const float* a = adj + bn * NN;
#pragma unroll
    for (int m = 0; m < NN; ++m) {
        float v = s * a[m];
        o[m] = v > 0.f ? v : 0.f;
    }
}

extern "C" void kernel_launch(void* const* d_in, const int* in_sizes, int n_in,
                              void* d_out, int out_size, void* d_ws, size_t ws_size,
                              hipStream_t stream) {
    const float* x   = (const float*)d_in[0];   // (32,10,65536)
    const float* adj = (const float*)d_in[1];   // (32,10,10)
    const float* W   = (const float*)d_in[2];   // (64,65536)
    float* out = (float*)d_out;                 // (32,10,80)

    // workspace: Bfrag (2048*64 bf16x8 = 2 MiB) | partials (64*320*8 f32 = 640 KiB)
    bf16x8* Bfrag   = (bf16x8*)d_ws;
    float* partials = (float*)(Bfrag + (size_t)KBLOCKS * 64);

    // K1: W -> bf16 B-fragments. 2048 kblocks x 64 lanes = 512 blocks.
    wreduce_kernel<<<(KBLOCKS * 64) / 256, 256, 0, stream>>>(W, Bfrag);

    // K2: MFMA GEMV. 20 mtiles x 64 kgrps = 1280 blocks.
    gemv_mfma_kernel<<<MTILES * KGRPS, 256, 0, stream>>>(x, Bfrag, partials);

    // K3: finalize. 2560 (bn,h) pairs.
    finalize_kernel<<<(ROWS * HEADS + 255) / 256, 256, 0, stream>>>(partials, adj, out);
}

// Round 8
// 25.351 us; speedup vs baseline: 1.3762x; 1.1378x over previous
//
#include <hip/hip_runtime.h>
#include <hip/hip_bf16.h>

// Problem constants
#define BB 32
#define NN 10
#define IN_DIM 65536
#define HEADS 8
#define DD 8
#define ROWS (BB*NN)          // 320
#define MTILES (ROWS/16)      // 20
#define KGRPS 512             // one block per kgrp
#define KB_PER_GRP 4          // 4 MFMA kblocks (32 floats each) per kgrp
#define KFLOATS (KB_PER_GRP*32)   // 128 floats of k per block
#define PAIRS (ROWS*HEADS)    // 2560

typedef __attribute__((ext_vector_type(8))) short bf16x8;
typedef __attribute__((ext_vector_type(4))) float f32x4;

static __device__ __forceinline__ short f2bf(float f) {
    __hip_bfloat16 h = __float2bfloat16(f);
    return *reinterpret_cast<short*>(&h);
}

// ---------------------------------------------------------------------------
// Fused kernel: one block per kgrp (512 blocks = exactly 2/CU).
// Phase 1: read the block's 32KB W slice, bake bf16 B-fragments (d-summed)
//          into LDS using the R6-verified mfma_16x16x32 B layout:
//          lds_b[kbl][lane][i] = sum_d W[(lane&15)*8+d][kgrp*128+kbl*32+(lane>>4)*8+i]
// Phase 2: hold the 4 B-fragments in registers, stream x rows 0..319 for this
//          k-slice (each wave owns 5 mtiles), MFMA, write per-kgrp partials.
// x and W are each read exactly once device-wide; Bfrag never touches HBM.
// ---------------------------------------------------------------------------
__global__ __launch_bounds__(256, 2) void gemv_fused_kernel(const float* __restrict__ x,
                                                            const float* __restrict__ W,
                                                            float* __restrict__ partials) {
    const int kgrp = blockIdx.x;
    const int t    = threadIdx.x;
    const int lane = t & 63;
    const int wave = t >> 6;       // 0..3

    __shared__ bf16x8 lds_b[KB_PER_GRP][64];

    // ---- phase 1: W -> B fragments in LDS (mapping verified in R6) ----
    {
        const int kbl  = t >> 6;         // kblock-local 0..3
        const int head = lane & 15;
        const int kq   = lane >> 4;      // 0..3
        bf16x8 o = {0,0,0,0,0,0,0,0};
        if (head < HEADS) {
            float s0=0,s1=0,s2=0,s3=0,s4=0,s5=0,s6=0,s7=0;
            const float* wbase = W + (size_t)(head * DD) * IN_DIM
                               + kgrp * KFLOATS + kbl * 32 + kq * 8;
#pragma unroll
            for (int d = 0; d < DD; ++d) {
                const float4* p = (const float4*)(wbase + (size_t)d * IN_DIM);
                float4 lo = p[0], hi = p[1];
                s0 += lo.x; s1 += lo.y; s2 += lo.z; s3 += lo.w;
                s4 += hi.x; s5 += hi.y; s6 += hi.z; s7 += hi.w;
            }
            o[0]=f2bf(s0); o[1]=f2bf(s1); o[2]=f2bf(s2); o[3]=f2bf(s3);
            o[4]=f2bf(s4); o[5]=f2bf(s5); o[6]=f2bf(s6); o[7]=f2bf(s7);
        }
        lds_b[kbl][lane] = o;
    }
    __syncthreads();

    const bf16x8 b0 = lds_b[0][lane];
    const bf16x8 b1 = lds_b[1][lane];
    const bf16x8 b2 = lds_b[2][lane];
    const bf16x8 b3 = lds_b[3][lane];

    // ---- phase 2: stream x, MFMA per mtile ----
    const int kq   = lane >> 4;
    const int head = lane & 15;
    const int r0   = (lane >> 4) * 4;
    const size_t xoff = (size_t)kgrp * KFLOATS + kq * 8;
    float* pbase = partials + (size_t)kgrp * PAIRS;

#pragma unroll
    for (int m = 0; m < MTILES / 4; ++m) {     // 5 mtiles per wave
        const int mtile = wave * (MTILES / 4) + m;
        const int row   = mtile * 16 + (lane & 15);
        const float* xr = x + (size_t)row * IN_DIM + xoff;

        f32x4 acc = {0.f, 0.f, 0.f, 0.f};
        {
            const float4* p = (const float4*)(xr + 0 * 32);
            float4 lo = p[0], hi = p[1];
            bf16x8 a;
            a[0]=f2bf(lo.x); a[1]=f2bf(lo.y); a[2]=f2bf(lo.z); a[3]=f2bf(lo.w);
            a[4]=f2bf(hi.x); a[5]=f2bf(hi.y); a[6]=f2bf(hi.z); a[7]=f2bf(hi.w);
            acc = __builtin_amdgcn_mfma_f32_16x16x32_bf16(a, b0, acc, 0, 0, 0);
        }
        {
            const float4* p = (const float4*)(xr + 1 * 32);
            float4 lo = p[0], hi = p[1];
            bf16x8 a;
            a[0]=f2bf(lo.x); a[1]=f2bf(lo.y); a[2]=f2bf(lo.z); a[3]=f2bf(lo.w);
            a[4]=f2bf(hi.x); a[5]=f2bf(hi.y); a[6]=f2bf(hi.z); a[7]=f2bf(hi.w);
            acc = __builtin_amdgcn_mfma_f32_16x16x32_bf16(a, b1, acc, 0, 0, 0);
        }
        {
            const float4* p = (const float4*)(xr + 2 * 32);
            float4 lo = p[0], hi = p[1];
            bf16x8 a;
            a[0]=f2bf(lo.x); a[1]=f2bf(lo.y); a[2]=f2bf(lo.z); a[3]=f2bf(lo.w);
            a[4]=f2bf(hi.x); a[5]=f2bf(hi.y); a[6]=f2bf(hi.z); a[7]=f2bf(hi.w);
            acc = __builtin_amdgcn_mfma_f32_16x16x32_bf16(a, b2, acc, 0, 0, 0);
        }
        {
            const float4* p = (const float4*)(xr + 3 * 32);
            float4 lo = p[0], hi = p[1];
            bf16x8 a;
            a[0]=f2bf(lo.x); a[1]=f2bf(lo.y); a[2]=f2bf(lo.z); a[3]=f2bf(lo.w);
            a[4]=f2bf(hi.x); a[5]=f2bf(hi.y); a[6]=f2bf(hi.z); a[7]=f2bf(hi.w);
            acc = __builtin_amdgcn_mfma_f32_16x16x32_bf16(a, b3, acc, 0, 0, 0);
        }

        // C/D layout (m89-verified): col = lane&15 (head), row = (lane>>4)*4 + j
        if (head < HEADS) {
#pragma unroll
            for (int j = 0; j < 4; ++j)
                pbase[(size_t)(mtile * 16 + r0 + j) * HEADS + head] = acc[j];
        }
    }
}

// ---------------------------------------------------------------------------
// Finalize: tot[pair] = sum_g partials[g][pair];  pair = bn*8 + h
//           out[bn][h*10+m] = relu(tot * adj[bn][m])
// 160 blocks x 256 threads: block owns 16 pairs; thread (pr = t&15, gs = t>>4)
// sums 32 of the 512 kgrps; LDS-fold; first 16 threads write 10 outputs each.
// ---------------------------------------------------------------------------
__global__ __launch_bounds__(256) void finalize_kernel(const float* __restrict__ partials,
                                                       const float* __restrict__ adj,
                                                       float* __restrict__ out) {
    const int b  = blockIdx.x;       // 0..159
    const int t  = threadIdx.x;
    const int pr = t & 15;           // pair-in-block
    const int gs = t >> 4;           // 0..15 (each covers 32 kgrps)
    const int pair = b * 16 + pr;

    float s = 0.f;
    const float* p = partials + (size_t)gs * 32 * PAIRS + pair;
#pragma unroll 8
    for (int g = 0; g < 32; ++g)
        s += p[(size_t)g * PAIRS];

    __shared__ float red[16][16];
    red[gs][pr] = s;
    __syncthreads();

    if (t < 16) {
        float tot = 0.f;
#pragma unroll
        for (int i = 0; i < 16; ++i) tot += red[i][t];
        const int pair2 = b * 16 + t;
        const int bn = pair2 >> 3;
        const int h  = pair2 & 7;
        const float* a = adj + bn * NN;
        float* o = out + bn * (HEADS * NN) + h * NN;
#pragma unroll
        for (int m = 0; m < NN; ++m) {
            float v = tot * a[m];
            o[m] = v > 0.f ? v : 0.f;
        }
    }
}

extern "C" void kernel_launch(void* const* d_in, const int* in_sizes, int n_in,
                              void* d_out, int out_size, void* d_ws, size_t ws_size,
                              hipStream_t stream) {
    const float* x   = (const float*)d_in[0];   // (32,10,65536)
    const float* adj = (const float*)d_in[1];   // (32,10,10)
    const float* W   = (const float*)d_in[2];   // (64,65536)
    float* out = (float*)d_out;                 // (32,10,80)

    // workspace: partials (512 * 2560 f32 = 5.24 MB)
    float* partials = (float*)d_ws;

    // K1: fused W-bake + MFMA GEMV. 512 blocks (one per kgrp).
    gemv_fused_kernel<<<KGRPS, 256, 0, stream>>>(x, W, partials);

    // K2: finalize. 160 blocks.
    finalize_kernel<<<160, 256, 0, stream>>>(partials, adj, out);
}